// Round 1
// baseline (283.116 us; speedup 1.0000x reference)
//
#include <hip/hip_runtime.h>

// Problem constants (fixed by the reference): x = (8, 64, 256, 256) fp32, k=2.
#define H   256
#define W   256
#define HP  255          // H - k + 1
#define WP  255          // W - k + 1
#define PIX (HP * WP)    // 65025 outputs per (b,c) image
#define NBC 512          // 8 * 64
#define EPS 1e-6f

__global__ __launch_bounds__(256) void entropy_k2_kernel(
    const float* __restrict__ x, float* __restrict__ out)
{
    const int bc  = blockIdx.y;
    const int pix = blockIdx.x * 256 + threadIdx.x;
    if (pix >= PIX) return;

    // pix -> (i, j); division by constant 255 -> mul_hi magic, cheap
    const int i = pix / WP;
    const int j = pix - i * WP;

    const float* img = x + (size_t)bc * (H * W);
    const float* r0  = img + i * W + j;
    const float* r1  = r0 + W;

    const float w0 = r0[0];
    const float w1 = r0[1];
    const float w2 = r1[0];
    const float w3 = r1[1];

    const float s    = w0 + w1 + w2 + w3 + EPS;
    const float rinv = __builtin_amdgcn_rcpf(s);   // v_rcp_f32, ~1 ulp

    const float p0 = w0 * rinv;
    const float p1 = w1 * rinv;
    const float p2 = w2 * rinv;
    const float p3 = w3 * rinv;

    // natural log via fast path (v_log_f32 * ln2 under the hood)
    const float ent = p0 * __logf(p0 + EPS)
                    + p1 * __logf(p1 + EPS)
                    + p2 * __logf(p2 + EPS)
                    + p3 * __logf(p3 + EPS);

    out[(size_t)bc * PIX + pix] = -ent;
}

extern "C" void kernel_launch(void* const* d_in, const int* in_sizes, int n_in,
                              void* d_out, int out_size, void* d_ws, size_t ws_size,
                              hipStream_t stream)
{
    const float* x   = (const float*)d_in[0];
    float*       out = (float*)d_out;

    dim3 grid((PIX + 255) / 256, NBC);
    entropy_k2_kernel<<<grid, 256, 0, stream>>>(x, out);
}

// Round 2
// 237.075 us; speedup vs baseline: 1.1942x; 1.1942x over previous
//
#include <hip/hip_runtime.h>

// Problem constants (fixed by the reference): x = (8, 64, 256, 256) fp32, k=2.
#define H    256
#define W    256
#define HP   255          // H - k + 1
#define WP   255          // W - k + 1
#define PIX  (HP * WP)    // 65025 outputs per (b,c) image
#define NBC  512          // 8 * 64
#define EPS  1e-6f
#define LN2  0.69314718055994531f

// 64 groups of 4 outputs per row, 255 rows -> 16320 groups per image.
#define GROUPS_PER_IMG (HP * 64)

__global__ __launch_bounds__(256) void entropy_k2_kernel(
    const float* __restrict__ x, float* __restrict__ out)
{
    const int bc = blockIdx.y;
    const int t  = blockIdx.x * 256 + threadIdx.x;   // group id within image
    if (t >= GROUPS_PER_IMG) return;

    const int i  = t >> 6;          // row 0..254
    const int j0 = (t & 63) << 2;   // col 0,4,...,252  (16B aligned)

    const float* img = x + (size_t)bc * (H * W);
    const float* r0  = img + i * W + j0;
    const float* r1  = r0 + W;

    const float4 a4 = *(const float4*)r0;
    const float4 b4 = *(const float4*)r1;
    // 5th element: for j0==252 the m=3 window is invalid anyway; clamp to stay
    // in-bounds (j0+4==256 would read one float past the array on the last row
    // of the last image).
    const int j4 = (j0 + 4 < W) ? 4 : 3;
    const float a5 = r0[j4];
    const float b5 = r1[j4];

    const float a[5] = {a4.x, a4.y, a4.z, a4.w, a5};
    const float b[5] = {b4.x, b4.y, b4.z, b4.w, b5};

    float res[4];
#pragma unroll
    for (int m = 0; m < 4; ++m) {
        const float w0 = a[m], w1 = a[m + 1];
        const float w2 = b[m], w3 = b[m + 1];
        const float s    = w0 + w1 + w2 + w3 + EPS;
        const float rinv = __builtin_amdgcn_rcpf(s);     // v_rcp_f32
        const float p0 = w0 * rinv;
        const float p1 = w1 * rinv;
        const float p2 = w2 * rinv;
        const float p3 = w3 * rinv;
        // native v_log_f32 is log2; fold ln(2) into the final scale
        const float acc = p0 * __builtin_amdgcn_logf(p0 + EPS)
                        + p1 * __builtin_amdgcn_logf(p1 + EPS)
                        + p2 * __builtin_amdgcn_logf(p2 + EPS)
                        + p3 * __builtin_amdgcn_logf(p3 + EPS);
        res[m] = -LN2 * acc;
    }

    float* o = out + (size_t)bc * PIX + i * WP + j0;
#pragma unroll
    for (int m = 0; m < 4; ++m)
        if (j0 + m < WP) o[m] = res[m];
}

extern "C" void kernel_launch(void* const* d_in, const int* in_sizes, int n_in,
                              void* d_out, int out_size, void* d_ws, size_t ws_size,
                              hipStream_t stream)
{
    const float* x   = (const float*)d_in[0];
    float*       out = (float*)d_out;

    dim3 grid((GROUPS_PER_IMG + 255) / 256, NBC);
    entropy_k2_kernel<<<grid, 256, 0, stream>>>(x, out);
}